// Round 3
// baseline (303.185 us; speedup 1.0000x reference)
//
#include <hip/hip_runtime.h>

// AlphaCompositionShader: B=4,H=512,W=512,K=8.
// R2: thread-per-pixel compute + explicit LDS transpose so ALL big global
// arrays (colors in, human_images out) are accessed 16B/lane coalesced.
// z/labels are loaded direct (2x16B per thread, lines fully consumed).
// LDS row stride 9 float4 -> (pix+k)%8 quad-bank spread = minimal aliasing.
// Outputs concatenated in d_out (float32):
//   [0,4P) image | [4P,5P) depth | [5P,6P) label | [6P,38P) human

#define BKG_DEPTH 100.0f
#define KD 8

__global__ __launch_bounds__(256) void alpha_comp_kernel(
    const float4* __restrict__ pc,   // P*8 rgba fragments
    const float4* __restrict__ zb,   // P*2 float4 (8 z per pixel)
    const int4*   __restrict__ lb,   // P*2 int4  (8 labels per pixel)
    const float*  __restrict__ bg,   // 3 floats
    float* __restrict__ out,
    int P)
{
    __shared__ float4 lds[256 * 9];            // 36,864 B; row = pixel, stride 9

    const int t = threadIdx.x;
    const int pix = blockIdx.x * 256 + t;      // P is an exact multiple of 256
    const size_t fragBase = (size_t)blockIdx.x * 2048;  // 256 pixels * 8 frags

    const float bg0 = bg[0], bg1 = bg[1], bg2 = bg[2];

    // ---- phase 1: coalesced global -> LDS transpose (colors)
#pragma unroll
    for (int i = 0; i < 8; ++i) {
        const int f = i * 256 + t;             // local fragment index
        const float4 v = pc[fragBase + f];     // 16B/lane, lane-consecutive
        lds[(f >> 3) * 9 + (f & 7)] = v;
    }
    __syncthreads();

    // ---- phase 2: per-pixel compute from own LDS row
    float4 c[KD];
#pragma unroll
    for (int k = 0; k < KD; ++k) c[k] = lds[t * 9 + k];

    const float4 z0 = zb[(size_t)pix * 2 + 0];
    const float4 z1 = zb[(size_t)pix * 2 + 1];
    const float z[KD] = {z0.x, z0.y, z0.z, z0.w, z1.x, z1.y, z1.z, z1.w};

    const int4 l0 = lb[(size_t)pix * 2 + 0];
    const int4 l1 = lb[(size_t)pix * 2 + 1];
    const int lbl[KD] = {l0.x, l0.y, l0.z, l0.w, l1.x, l1.y, l1.z, l1.w};

    // composite: back-to-front scan (k = K-1 .. 0)
    float r = bg0, g = bg1, b = bg2;
    float a = 0.0f, d = BKG_DEPTH, lab = (float)KD;
#pragma unroll
    for (int k = KD - 1; k >= 0; --k) {
        const float alpha = c[k].w;
        const float ia = 1.0f - alpha;
        r = c[k].x * alpha + r * ia;
        g = c[k].y * alpha + g * ia;
        b = c[k].z * alpha + b * ia;
        a = fmaxf(alpha, a);
        if (z[k] > 0.0f) d = z[k] * alpha + d * ia;
        if (!(z[k] < 0.0f) && alpha > 0.5f) lab = (float)lbl[k];
    }
    const float labv = (lab > (float)KD - 0.5f) ? -1.0f : lab;

    // human images: per label n, front-most fragment with z>=0 && lbl==n
    float4 hv[KD];
#pragma unroll
    for (int n = 0; n < KD; ++n) {
        float4 gat = make_float4(0.0f, 0.0f, 0.0f, 0.0f);
#pragma unroll
        for (int k = KD - 1; k >= 0; --k) {
            if (!(z[k] < 0.0f) && lbl[k] == n) gat = c[k];
        }
        const float alpha = gat.w;
        const float ia = 1.0f - alpha;
        hv[n] = make_float4(gat.x * alpha + bg0 * ia,
                            gat.y * alpha + bg1 * ia,
                            gat.z * alpha + bg2 * ia,
                            alpha);
    }

    // coalesced direct stores for the small outputs
    ((float4*)out)[pix] = make_float4(r, g, b, a);
    out[(size_t)4 * P + pix] = d;
    out[(size_t)5 * P + pix] = labv;

    // ---- phase 3: human through LDS (reuse buffer; own-row write is safe)
#pragma unroll
    for (int n = 0; n < KD; ++n) lds[t * 9 + n] = hv[n];
    __syncthreads();

    float4* outH = (float4*)(out + (size_t)6 * P);
#pragma unroll
    for (int i = 0; i < 8; ++i) {
        const int f = i * 256 + t;
        outH[fragBase + f] = lds[(f >> 3) * 9 + (f & 7)];  // 16B/lane coalesced
    }
}

extern "C" void kernel_launch(void* const* d_in, const int* in_sizes, int n_in,
                              void* d_out, int out_size, void* d_ws, size_t ws_size,
                              hipStream_t stream) {
    const float4* pc = (const float4*)d_in[0];   // pixel_colors (B,H,W,K,4) f32
    const float4* zb = (const float4*)d_in[1];   // zbuf (B,H,W,K) f32
    const int4*   lb = (const int4*)d_in[2];     // pixel_labels (B,H,W,K) i32
    const float*  bg = (const float*)d_in[3];    // background_color (3,) f32
    float* out = (float*)d_out;

    const int P = in_sizes[1] / KD;              // B*H*W = 1048576 (multiple of 256)
    const int block = 256;
    const int grid = P / block;
    alpha_comp_kernel<<<grid, block, 0, stream>>>(pc, zb, lb, bg, out, P);
}